// Round 1
// baseline (3629.816 us; speedup 1.0000x reference)
//
#include <hip/hip_runtime.h>
#include <math.h>

#define FEAT 2048
#define HD 1024
#define FH 4096
#define NN 8192

__device__ __forceinline__ float sigmoidf_(float x) { return 1.0f / (1.0f + expf(-x)); }
__device__ __forceinline__ float4 add4_(float4 a, float4 b) {
    return make_float4(a.x + b.x, a.y + b.y, a.z + b.z, a.w + b.w);
}

// ---------------------------------------------------------------------------
// xproj[n][j] = sum_k feat[n][k] * Wx[j][k] + bx[j] + bh[j]
// Tiles: BM=64, BN=64, BK=32. 256 threads, each computes 4x4 outputs.
// ---------------------------------------------------------------------------
__global__ __launch_bounds__(256) void xproj_kernel(
    const float* __restrict__ feat, const float* __restrict__ Wx,
    const float* __restrict__ bx, const float* __restrict__ bh,
    float* __restrict__ xproj)
{
    __shared__ float As[32][68];  // [k][m], pad 4 keeps 16B alignment, breaks pow2 stride
    __shared__ float Bs[32][68];  // [k][n]
    const int bm = blockIdx.x * 64;
    const int bn = blockIdx.y * 64;
    const int tid = threadIdx.x;
    const int tx = tid & 15, ty = tid >> 4;
    const int srow = tid >> 3;        // 0..31
    const int scol = (tid & 7) * 4;   // 0..28
    float acc[4][4] = {};

    for (int k0 = 0; k0 < FEAT; k0 += 32) {
        #pragma unroll
        for (int half = 0; half < 2; ++half) {
            const int r = srow + half * 32;
            const float4 va = *(const float4*)(feat + (size_t)(bm + r) * FEAT + k0 + scol);
            As[scol + 0][r] = va.x; As[scol + 1][r] = va.y;
            As[scol + 2][r] = va.z; As[scol + 3][r] = va.w;
            const float4 vb = *(const float4*)(Wx + (size_t)(bn + r) * FEAT + k0 + scol);
            Bs[scol + 0][r] = vb.x; Bs[scol + 1][r] = vb.y;
            Bs[scol + 2][r] = vb.z; Bs[scol + 3][r] = vb.w;
        }
        __syncthreads();
        #pragma unroll
        for (int k = 0; k < 32; ++k) {
            const float4 a = *(const float4*)(&As[k][ty * 4]);
            const float4 b = *(const float4*)(&Bs[k][tx * 4]);
            const float av[4] = {a.x, a.y, a.z, a.w};
            const float bv[4] = {b.x, b.y, b.z, b.w};
            #pragma unroll
            for (int i = 0; i < 4; ++i)
                #pragma unroll
                for (int j = 0; j < 4; ++j)
                    acc[i][j] = fmaf(av[i], bv[j], acc[i][j]);
        }
        __syncthreads();
    }
    #pragma unroll
    for (int i = 0; i < 4; ++i) {
        const int n = bm + ty * 4 + i;
        #pragma unroll
        for (int j = 0; j < 4; ++j) {
            const int col = bn + tx * 4 + j;
            xproj[(size_t)n * FH + col] = acc[i][j] + bx[col] + bh[col];
        }
    }
}

// ---------------------------------------------------------------------------
// Per tree level: for node t in [start, start+count):
//   iofu = xproj[t] + h_buf[parent[t]+1] @ Wh^T ; gates ; h,c,out
// Block tile: 32 nodes x 32 within-gate cols (= 128 Wh rows: 4 gates x 32).
// Gate g's columns are Wh rows g*1024 + jg0 + [0,32) -> all 4 gates block-local.
// ---------------------------------------------------------------------------
__global__ __launch_bounds__(256) void level_kernel(
    const float* __restrict__ xproj, const float* __restrict__ Wh,
    const int* __restrict__ parent, float* __restrict__ h_buf,
    float* __restrict__ c_buf, float* __restrict__ out,
    int start, int count)
{
    __shared__ float As[32][36];    // [k][node]
    __shared__ float Bs[32][132];   // [k][whrow-in-tile]
    __shared__ float S[32][132];    // iofu accumulator tile [node][whrow-in-tile]

    const int t0 = start + blockIdx.x * 32;
    const int jg0 = blockIdx.y * 32;
    const int tid = threadIdx.x;
    const int tx = tid & 31, ty = tid >> 5;   // tx 0..31 (cols), ty 0..7 (rows)
    const int lim = start + count;

    float acc[4][4] = {};

    const int arow = tid >> 3;          // 0..31
    const int acol = (tid & 7) * 4;     // 0..28
    const int ta = t0 + arow;
    const bool avalid = (ta < lim);
    const int pa = avalid ? parent[ta] : -1;
    const float* hp_base = h_buf + (size_t)(pa + 1) * HD;

    for (int k0 = 0; k0 < HD; k0 += 32) {
        // stage A: gathered parent-h rows [32 nodes][32 k]
        {
            float4 va = make_float4(0.f, 0.f, 0.f, 0.f);
            if (avalid) va = *(const float4*)(hp_base + k0 + acol);
            As[acol + 0][arow] = va.x; As[acol + 1][arow] = va.y;
            As[acol + 2][arow] = va.z; As[acol + 3][arow] = va.w;
        }
        // stage B: 128 Wh rows x 32 k
        #pragma unroll
        for (int q = 0; q < 4; ++q) {
            const int r = (tid >> 3) + q * 32;                      // 0..127
            const int whrow = ((r >> 5) << 10) + jg0 + (r & 31);    // gate*1024 + jg0 + col
            const float4 vb = *(const float4*)(Wh + (size_t)whrow * HD + k0 + acol);
            Bs[acol + 0][r] = vb.x; Bs[acol + 1][r] = vb.y;
            Bs[acol + 2][r] = vb.z; Bs[acol + 3][r] = vb.w;
        }
        __syncthreads();
        #pragma unroll
        for (int k = 0; k < 32; ++k) {
            const float4 a = *(const float4*)(&As[k][ty * 4]);
            const float4 b = *(const float4*)(&Bs[k][tx * 4]);
            const float av[4] = {a.x, a.y, a.z, a.w};
            const float bv[4] = {b.x, b.y, b.z, b.w};
            #pragma unroll
            for (int i = 0; i < 4; ++i)
                #pragma unroll
                for (int j = 0; j < 4; ++j)
                    acc[i][j] = fmaf(av[i], bv[j], acc[i][j]);
        }
        __syncthreads();
    }

    // spill acc tile to LDS so gating can read all 4 gates per column
    #pragma unroll
    for (int i = 0; i < 4; ++i)
        #pragma unroll
        for (int j = 0; j < 4; ++j)
            S[ty * 4 + i][tx * 4 + j] = acc[i][j];
    __syncthreads();

    // gating: 32 nodes x 32 cols, 4 per thread (float4)
    const int grow = tid >> 3;
    const int gcol = (tid & 7) * 4;
    const int t = t0 + grow;
    if (t < lim) {
        const int p = parent[t];
        const size_t xbase = (size_t)t * FH + jg0 + gcol;
        const float4 xi = *(const float4*)(xproj + xbase);
        const float4 xo = *(const float4*)(xproj + xbase + HD);
        const float4 xf = *(const float4*)(xproj + xbase + 2 * HD);
        const float4 xu = *(const float4*)(xproj + xbase + 3 * HD);
        const float4 si = *(const float4*)(&S[grow][gcol]);
        const float4 so = *(const float4*)(&S[grow][32 + gcol]);
        const float4 sf = *(const float4*)(&S[grow][64 + gcol]);
        const float4 su = *(const float4*)(&S[grow][96 + gcol]);
        const float4 cpv = *(const float4*)(c_buf + (size_t)(p + 1) * HD + jg0 + gcol);

        float ii[4], oo[4], ff[4], uu[4], cp4[4], cc[4], hh[4];
        *(float4*)ii = add4_(si, xi);
        *(float4*)oo = add4_(so, xo);
        *(float4*)ff = add4_(sf, xf);
        *(float4*)uu = add4_(su, xu);
        *(float4*)cp4 = cpv;
        #pragma unroll
        for (int q = 0; q < 4; ++q) {
            const float c = sigmoidf_(ii[q]) * tanhf(uu[q]) + sigmoidf_(ff[q]) * cp4[q];
            cc[q] = c;
            hh[q] = sigmoidf_(oo[q]) * tanhf(c);
        }
        *(float4*)(c_buf + (size_t)(t + 1) * HD + jg0 + gcol) = *(const float4*)cc;
        *(float4*)(h_buf + (size_t)(t + 1) * HD + jg0 + gcol) = *(const float4*)hh;
        *(float4*)(out + (size_t)t * HD + jg0 + gcol) = *(const float4*)hh;
    }
}

__global__ __launch_bounds__(256) void init_kernel(
    const float* __restrict__ root_h, const float* __restrict__ root_c,
    float* __restrict__ h_buf, float* __restrict__ c_buf)
{
    const int i = blockIdx.x * 256 + threadIdx.x;
    if (i < HD) { h_buf[i] = root_h[i]; c_buf[i] = root_c[i]; }
}

extern "C" void kernel_launch(void* const* d_in, const int* in_sizes, int n_in,
                              void* d_out, int out_size, void* d_ws, size_t ws_size,
                              hipStream_t stream) {
    const float* feat   = (const float*)d_in[0];
    const float* Wx     = (const float*)d_in[1];
    const float* bx     = (const float*)d_in[2];
    const float* Wh     = (const float*)d_in[3];
    const float* bh     = (const float*)d_in[4];
    const int*   parent = (const int*)d_in[5];
    const float* root_c = (const float*)d_in[6];
    const float* root_h = (const float*)d_in[7];
    float* out = (float*)d_out;

    char* ws = (char*)d_ws;
    float* xproj = (float*)ws;                                   // N*4H f32 = 128 MB
    float* h_buf = (float*)(ws + (size_t)NN * FH * sizeof(float)); // (N+1)*H
    float* c_buf = h_buf + (size_t)(NN + 1) * HD;                  // (N+1)*H

    init_kernel<<<4, 256, 0, stream>>>(root_h, root_c, h_buf, c_buf);

    dim3 g1(NN / 64, FH / 64);
    xproj_kernel<<<g1, 256, 0, stream>>>(feat, Wx, bx, bh, xproj);

    for (int start = 0, sz = 1; start < NN; start += sz, sz *= 2) {
        const int count = (sz < NN - start) ? sz : (NN - start);
        dim3 g2((count + 31) / 32, HD / 32);
        level_kernel<<<g2, 256, 0, stream>>>(xproj, Wh, parent, h_buf, c_buf, out,
                                             start, count);
    }
}

// Round 2
// 594.506 us; speedup vs baseline: 6.1056x; 6.1056x over previous
//
#include <hip/hip_runtime.h>
#include <math.h>

#define FEAT 2048
#define HD 1024
#define FH 4096
#define NN 8192

using s16x8 = __attribute__((ext_vector_type(8))) short;
using f32x4 = __attribute__((ext_vector_type(4))) float;

#define GLOBAL_AS __attribute__((address_space(1)))
#define LDS_AS __attribute__((address_space(3)))

__device__ __forceinline__ void gload_lds16(const void* g, void* l) {
    __builtin_amdgcn_global_load_lds((const GLOBAL_AS unsigned int*)g,
                                     (LDS_AS unsigned int*)l, 16, 0, 0);
}

__device__ __forceinline__ unsigned short f2bf(float f) {
    union { float f; unsigned u; } v; v.f = f;
    unsigned r = v.u + 0x7FFFu + ((v.u >> 16) & 1u);  // RNE
    return (unsigned short)(r >> 16);
}

__device__ __forceinline__ float fast_sig(float x) { return 1.0f / (1.0f + __expf(-x)); }
__device__ __forceinline__ float fast_tanh(float x) {
    float ax = fabsf(x);
    float e = __expf(2.0f * ax);
    float r = 1.0f - 2.0f / (e + 1.0f);
    return copysignf(r, x);
}

// ---------------------------------------------------------------------------
// fp32 -> bf16 bulk convert (n multiple of 8)
// ---------------------------------------------------------------------------
__global__ __launch_bounds__(256) void f32_to_bf16_kernel(
    const float* __restrict__ src, unsigned short* __restrict__ dst, int n)
{
    int i = (blockIdx.x * 256 + threadIdx.x) * 8;
    if (i >= n) return;
    float4 a = *(const float4*)(src + i);
    float4 b = *(const float4*)(src + i + 4);
    unsigned short r[8] = {f2bf(a.x), f2bf(a.y), f2bf(a.z), f2bf(a.w),
                           f2bf(b.x), f2bf(b.y), f2bf(b.z), f2bf(b.w)};
    *(s16x8*)(dst + i) = *(const s16x8*)r;
}

__global__ __launch_bounds__(256) void init_kernel(
    const float* __restrict__ root_h, const float* __restrict__ root_c,
    unsigned short* __restrict__ h_buf, float* __restrict__ c_buf)
{
    const int i = blockIdx.x * 256 + threadIdx.x;
    if (i < HD) { h_buf[i] = f2bf(root_h[i]); c_buf[i] = root_c[i]; }
}

// ---------------------------------------------------------------------------
// xproj[n][j] = feat[n][:] . Wx[j][:] + bx[j] + bh[j]     (bf16 MFMA, fp32 out)
// m97 structure: 128x128 tile, BK=32, 4 waves (2x2), acc 4x4 of 16x16x32.
// ---------------------------------------------------------------------------
__global__ __launch_bounds__(256) void xproj_mfma(
    const unsigned short* __restrict__ Ab,   // feat_b [8192][2048]
    const unsigned short* __restrict__ Bb,   // Wx_b   [4096][2048]
    const float* __restrict__ bx, const float* __restrict__ bh,
    float* __restrict__ xproj)
{
    __shared__ unsigned short As[128 * 32];  // [row][k], 64B rows
    __shared__ unsigned short Bs[128 * 32];
    const int tid = threadIdx.x;
    const int wid = tid >> 6;
    const int lane = tid & 63;
    const int bm = blockIdx.x * 128;
    const int bn = blockIdx.y * 128;
    const int wm = (wid & 1) * 64;
    const int wn = (wid >> 1) * 64;

    // staging slot: issue q: row = q*64 + wid*16 + lane/4, k-offset (lane&3)*8 (bf16)
    const int srow = wid * 16 + (lane >> 2);
    const int sk = (lane & 3) * 8;
    const unsigned short* gA0 = Ab + (size_t)(bm + srow) * FEAT + sk;
    const unsigned short* gA1 = Ab + (size_t)(bm + 64 + srow) * FEAT + sk;
    const unsigned short* gB0 = Bb + (size_t)(bn + srow) * FEAT + sk;
    const unsigned short* gB1 = Bb + (size_t)(bn + 64 + srow) * FEAT + sk;
    unsigned short* lA0 = As + wid * 512;          // bytes: wid*1024
    unsigned short* lA1 = As + 2048 + wid * 512;
    unsigned short* lB0 = Bs + wid * 512;
    unsigned short* lB1 = Bs + 2048 + wid * 512;

    f32x4 acc[4][4];
    #pragma unroll
    for (int i = 0; i < 4; ++i)
        #pragma unroll
        for (int j = 0; j < 4; ++j) { f32x4 z = {0.f, 0.f, 0.f, 0.f}; acc[i][j] = z; }

    const int fr = lane & 15;
    const int fk = (lane >> 4) * 8;   // bf16 offset within 32-wide k row

    for (int k0 = 0; k0 < FEAT; k0 += 32) {
        gload_lds16(gA0 + k0, lA0);
        gload_lds16(gA1 + k0, lA1);
        gload_lds16(gB0 + k0, lB0);
        gload_lds16(gB1 + k0, lB1);
        __syncthreads();   // compiler emits vmcnt(0) drain here (m97 semantics)

        s16x8 aF[4], bF[4];
        #pragma unroll
        for (int i = 0; i < 4; ++i)
            aF[i] = *(const s16x8*)&As[(wm + i * 16 + fr) * 32 + fk];
        #pragma unroll
        for (int j = 0; j < 4; ++j)
            bF[j] = *(const s16x8*)&Bs[(wn + j * 16 + fr) * 32 + fk];
        #pragma unroll
        for (int i = 0; i < 4; ++i)
            #pragma unroll
            for (int j = 0; j < 4; ++j)
                acc[i][j] = __builtin_amdgcn_mfma_f32_16x16x32_bf16(aF[i], bF[j], acc[i][j], 0, 0, 0);
        __syncthreads();
    }

    // D layout: row = (lane>>4)*4 + reg, col = lane&15 (m89-verified)
    const int fq = lane >> 4;
    #pragma unroll
    for (int j = 0; j < 4; ++j) {
        const int col = bn + wn + j * 16 + fr;
        const float bias = bx[col] + bh[col];
        #pragma unroll
        for (int i = 0; i < 4; ++i) {
            const int rowb = bm + wm + i * 16 + fq * 4;
            #pragma unroll
            for (int reg = 0; reg < 4; ++reg)
                xproj[(size_t)(rowb + reg) * FH + col] = acc[i][j][reg] + bias;
        }
    }
}

// ---------------------------------------------------------------------------
// Per tree level, fused: iofu = xproj[t] + h[parent] @ Wh^T ; gates ; h,c,out.
// Block: 128 nodes x 32 within-gate cols. Wave w: nodes (w&1)*64 +[0,64),
// cols (w>>1)*16 +[0,16). B-fragments = the 4 gates at those cols, so each
// lane holds i/o/f/u for its (node,col) in acc[i][g] registers -> no spill.
// ---------------------------------------------------------------------------
__global__ __launch_bounds__(256) void level_mfma(
    const float* __restrict__ xproj, const unsigned short* __restrict__ Whb,
    const int* __restrict__ parent, unsigned short* __restrict__ h_buf,
    float* __restrict__ c_buf, float* __restrict__ out,
    int start, int count)
{
    __shared__ unsigned short As[128 * 32];  // [node][k]
    __shared__ unsigned short Bs[128 * 32];  // [gate*32 + within-gate col][k]
    const int tid = threadIdx.x;
    const int wid = tid >> 6;
    const int lane = tid & 63;
    const int t0 = start + blockIdx.x * 128;
    const int jg0 = blockIdx.y * 32;
    const int lim = start + count;
    const int wm = (wid & 1) * 64;
    const int wn16 = (wid >> 1) * 16;

    const int srow = wid * 16 + (lane >> 2);
    const int sk = (lane & 3) * 8;
    // A: gathered parent-h rows (bf16), clamped for OOB nodes
    const int tA0 = min(t0 + srow, lim - 1);
    const int tA1 = min(t0 + 64 + srow, lim - 1);
    const unsigned short* gA0 = h_buf + (size_t)(parent[tA0] + 1) * HD + sk;
    const unsigned short* gA1 = h_buf + (size_t)(parent[tA1] + 1) * HD + sk;
    // B: tile row r -> Wh row (r>>5)*1024 + jg0 + (r&31)
    const int r0 = srow, r1 = 64 + srow;
    const unsigned short* gB0 = Whb + (size_t)((r0 >> 5) * HD + jg0 + (r0 & 31)) * HD + sk;
    const unsigned short* gB1 = Whb + (size_t)((r1 >> 5) * HD + jg0 + (r1 & 31)) * HD + sk;
    unsigned short* lA0 = As + wid * 512;
    unsigned short* lA1 = As + 2048 + wid * 512;
    unsigned short* lB0 = Bs + wid * 512;
    unsigned short* lB1 = Bs + 2048 + wid * 512;

    f32x4 acc[4][4];
    #pragma unroll
    for (int i = 0; i < 4; ++i)
        #pragma unroll
        for (int g = 0; g < 4; ++g) { f32x4 z = {0.f, 0.f, 0.f, 0.f}; acc[i][g] = z; }

    const int fr = lane & 15;
    const int fk = (lane >> 4) * 8;

    for (int k0 = 0; k0 < HD; k0 += 32) {
        gload_lds16(gA0 + k0, lA0);
        gload_lds16(gA1 + k0, lA1);
        gload_lds16(gB0 + k0, lB0);
        gload_lds16(gB1 + k0, lB1);
        __syncthreads();

        s16x8 aF[4], bF[4];
        #pragma unroll
        for (int i = 0; i < 4; ++i)
            aF[i] = *(const s16x8*)&As[(wm + i * 16 + fr) * 32 + fk];
        #pragma unroll
        for (int g = 0; g < 4; ++g)
            bF[g] = *(const s16x8*)&Bs[(g * 32 + wn16 + fr) * 32 + fk];
        #pragma unroll
        for (int i = 0; i < 4; ++i)
            #pragma unroll
            for (int g = 0; g < 4; ++g)
                acc[i][g] = __builtin_amdgcn_mfma_f32_16x16x32_bf16(aF[i], bF[g], acc[i][g], 0, 0, 0);
        __syncthreads();
    }

    const int fq = lane >> 4;
    const int col = jg0 + wn16 + fr;  // within-gate column, 0..1023
    #pragma unroll
    for (int i = 0; i < 4; ++i) {
        #pragma unroll
        for (int reg = 0; reg < 4; ++reg) {
            const int t = t0 + wm + i * 16 + fq * 4 + reg;
            if (t < lim) {
                const int p = parent[t];
                const size_t xb = (size_t)t * FH + col;
                const float gi = acc[i][0][reg] + xproj[xb];
                const float go = acc[i][1][reg] + xproj[xb + HD];
                const float gf = acc[i][2][reg] + xproj[xb + 2 * HD];
                const float gu = acc[i][3][reg] + xproj[xb + 3 * HD];
                const float cp = c_buf[(size_t)(p + 1) * HD + col];
                const float c = fast_sig(gi) * fast_tanh(gu) + fast_sig(gf) * cp;
                const float h = fast_sig(go) * fast_tanh(c);
                c_buf[(size_t)(t + 1) * HD + col] = c;
                h_buf[(size_t)(t + 1) * HD + col] = f2bf(h);
                out[(size_t)t * HD + col] = h;
            }
        }
    }
}

extern "C" void kernel_launch(void* const* d_in, const int* in_sizes, int n_in,
                              void* d_out, int out_size, void* d_ws, size_t ws_size,
                              hipStream_t stream) {
    const float* feat   = (const float*)d_in[0];
    const float* Wx     = (const float*)d_in[1];
    const float* bx     = (const float*)d_in[2];
    const float* Wh     = (const float*)d_in[3];
    const float* bh     = (const float*)d_in[4];
    const int*   parent = (const int*)d_in[5];
    const float* root_c = (const float*)d_in[6];
    const float* root_h = (const float*)d_in[7];
    float* out = (float*)d_out;

    char* ws = (char*)d_ws;
    float* xproj = (float*)ws;                          ws += (size_t)NN * FH * 4;          // 128 MB
    float* c_buf = (float*)ws;                          ws += (size_t)(NN + 1) * HD * 4;    // 32 MB
    unsigned short* feat_b = (unsigned short*)ws;       ws += (size_t)NN * FEAT * 2;        // 32 MB
    unsigned short* Wx_b = (unsigned short*)ws;         ws += (size_t)FH * FEAT * 2;        // 16 MB
    unsigned short* Wh_b = (unsigned short*)ws;         ws += (size_t)FH * HD * 2;          // 8 MB
    unsigned short* h_buf = (unsigned short*)ws;        ws += (size_t)(NN + 1) * HD * 2;    // 16 MB

    f32_to_bf16_kernel<<<(NN * FEAT) / 8 / 256, 256, 0, stream>>>(feat, feat_b, NN * FEAT);
    f32_to_bf16_kernel<<<(FH * FEAT) / 8 / 256, 256, 0, stream>>>(Wx, Wx_b, FH * FEAT);
    f32_to_bf16_kernel<<<(FH * HD) / 8 / 256, 256, 0, stream>>>(Wh, Wh_b, FH * HD);
    init_kernel<<<4, 256, 0, stream>>>(root_h, root_c, h_buf, c_buf);

    dim3 g1(NN / 128, FH / 128);
    xproj_mfma<<<g1, 256, 0, stream>>>(feat_b, Wx_b, bx, bh, xproj);

    for (int start = 0, sz = 1; start < NN; start += sz, sz *= 2) {
        const int count = (sz < NN - start) ? sz : (NN - start);
        dim3 g2((count + 127) / 128, HD / 32);
        level_mfma<<<g2, 256, 0, stream>>>(xproj, Wh_b, parent, h_buf, c_buf, out,
                                           start, count);
    }
}

// Round 3
// 581.498 us; speedup vs baseline: 6.2422x; 1.0224x over previous
//
#include <hip/hip_runtime.h>
#include <math.h>

#define FEAT 2048
#define HD 1024
#define FH 4096
#define NN 8192

using s16x8 = __attribute__((ext_vector_type(8))) short;
using f32x4 = __attribute__((ext_vector_type(4))) float;

#define GLOBAL_AS __attribute__((address_space(1)))
#define LDS_AS __attribute__((address_space(3)))

__device__ __forceinline__ void gload_lds16(const void* g, void* l) {
    __builtin_amdgcn_global_load_lds((const GLOBAL_AS unsigned int*)g,
                                     (LDS_AS unsigned int*)l, 16, 0, 0);
}

__device__ __forceinline__ unsigned short f2bf(float f) {
    union { float f; unsigned u; } v; v.f = f;
    unsigned r = v.u + 0x7FFFu + ((v.u >> 16) & 1u);  // RNE
    return (unsigned short)(r >> 16);
}

__device__ __forceinline__ float fast_sig(float x) { return 1.0f / (1.0f + __expf(-x)); }
__device__ __forceinline__ float fast_tanh(float x) {
    float ax = fabsf(x);
    float e = __expf(2.0f * ax);
    float r = 1.0f - 2.0f / (e + 1.0f);
    return copysignf(r, x);
}

// ---------------------------------------------------------------------------
// fused fp32 -> bf16 convert for feat, Wx, Wh (all sizes multiples of 8*256)
// ---------------------------------------------------------------------------
__global__ __launch_bounds__(256) void convert_all_kernel(
    const float* __restrict__ feat, const float* __restrict__ Wx,
    const float* __restrict__ Wh, unsigned short* __restrict__ feat_b,
    unsigned short* __restrict__ Wx_b, unsigned short* __restrict__ Wh_b)
{
    const size_t n1 = (size_t)NN * FEAT;
    const size_t n2 = n1 + (size_t)FH * FEAT;
    size_t i = ((size_t)blockIdx.x * 256 + threadIdx.x) * 8;
    const float* s; unsigned short* d;
    if (i < n1)      { s = feat + i;        d = feat_b + i; }
    else if (i < n2) { s = Wx + (i - n1);   d = Wx_b + (i - n1); }
    else             { s = Wh + (i - n2);   d = Wh_b + (i - n2); }
    float4 a = *(const float4*)s;
    float4 b = *(const float4*)(s + 4);
    unsigned short r[8] = {f2bf(a.x), f2bf(a.y), f2bf(a.z), f2bf(a.w),
                           f2bf(b.x), f2bf(b.y), f2bf(b.z), f2bf(b.w)};
    *(s16x8*)d = *(const s16x8*)r;
}

__global__ __launch_bounds__(256) void init_kernel(
    const float* __restrict__ root_h, const float* __restrict__ root_c,
    unsigned short* __restrict__ h_buf, float* __restrict__ c_buf)
{
    const int i = blockIdx.x * 256 + threadIdx.x;
    if (i < HD) { h_buf[i] = f2bf(root_h[i]); c_buf[i] = root_c[i]; }
}

// ---------------------------------------------------------------------------
// xproj[n][j] = feat[n][:] . Wx[j][:] + bx[j] + bh[j]   (bf16 MFMA, fp32 out)
// m97 structure: 128x128 tile, BK=32, 4 waves (2x2), acc 4x4. +XCD swizzle.
// ---------------------------------------------------------------------------
__global__ __launch_bounds__(256) void xproj_mfma(
    const unsigned short* __restrict__ Ab,   // feat_b [8192][2048]
    const unsigned short* __restrict__ Bb,   // Wx_b   [4096][2048]
    const float* __restrict__ bx, const float* __restrict__ bh,
    float* __restrict__ xproj)
{
    __shared__ unsigned short As[128 * 32];
    __shared__ unsigned short Bs[128 * 32];
    const int tid = threadIdx.x;
    const int wid = tid >> 6;
    const int lane = tid & 63;

    // bijective XCD swizzle over flattened grid (nwg = 64*32 = 2048, %8==0)
    int id = blockIdx.y * gridDim.x + blockIdx.x;
    const int cpx = (gridDim.x * gridDim.y) >> 3;
    id = (id & 7) * cpx + (id >> 3);
    const int bm = (id % gridDim.x) * 128;
    const int bn = (id / gridDim.x) * 128;

    const int wm = (wid & 1) * 64;
    const int wn = (wid >> 1) * 64;

    const int srow = wid * 16 + (lane >> 2);
    const int sk = (lane & 3) * 8;
    const unsigned short* gA0 = Ab + (size_t)(bm + srow) * FEAT + sk;
    const unsigned short* gA1 = Ab + (size_t)(bm + 64 + srow) * FEAT + sk;
    const unsigned short* gB0 = Bb + (size_t)(bn + srow) * FEAT + sk;
    const unsigned short* gB1 = Bb + (size_t)(bn + 64 + srow) * FEAT + sk;
    unsigned short* lA0 = As + wid * 512;
    unsigned short* lA1 = As + 2048 + wid * 512;
    unsigned short* lB0 = Bs + wid * 512;
    unsigned short* lB1 = Bs + 2048 + wid * 512;

    f32x4 acc[4][4];
    #pragma unroll
    for (int i = 0; i < 4; ++i)
        #pragma unroll
        for (int j = 0; j < 4; ++j) { f32x4 z = {0.f, 0.f, 0.f, 0.f}; acc[i][j] = z; }

    const int fr = lane & 15;
    const int fk = (lane >> 4) * 8;

    for (int k0 = 0; k0 < FEAT; k0 += 32) {
        gload_lds16(gA0 + k0, lA0);
        gload_lds16(gA1 + k0, lA1);
        gload_lds16(gB0 + k0, lB0);
        gload_lds16(gB1 + k0, lB1);
        __syncthreads();

        s16x8 aF[4], bF[4];
        #pragma unroll
        for (int i = 0; i < 4; ++i)
            aF[i] = *(const s16x8*)&As[(wm + i * 16 + fr) * 32 + fk];
        #pragma unroll
        for (int j = 0; j < 4; ++j)
            bF[j] = *(const s16x8*)&Bs[(wn + j * 16 + fr) * 32 + fk];
        #pragma unroll
        for (int i = 0; i < 4; ++i)
            #pragma unroll
            for (int j = 0; j < 4; ++j)
                acc[i][j] = __builtin_amdgcn_mfma_f32_16x16x32_bf16(aF[i], bF[j], acc[i][j], 0, 0, 0);
        __syncthreads();
    }

    const int fq = lane >> 4;
    #pragma unroll
    for (int j = 0; j < 4; ++j) {
        const int col = bn + wn + j * 16 + fr;
        const float bias = bx[col] + bh[col];
        #pragma unroll
        for (int i = 0; i < 4; ++i) {
            const int rowb = bm + wm + i * 16 + fq * 4;
            #pragma unroll
            for (int reg = 0; reg < 4; ++reg)
                xproj[(size_t)(rowb + reg) * FH + col] = acc[i][j][reg] + bias;
        }
    }
}

// ---------------------------------------------------------------------------
// Shared epilogue: gates from acc[i][g] + xproj, write c/h/out.
// ---------------------------------------------------------------------------
__device__ __forceinline__ void level_epilogue(
    f32x4 (&acc)[4][4], const float* __restrict__ xproj,
    const int* __restrict__ parent, unsigned short* __restrict__ h_buf,
    float* __restrict__ c_buf, float* __restrict__ out,
    int t0, int lim, int wm, int col, int fq)
{
    #pragma unroll
    for (int i = 0; i < 4; ++i) {
        #pragma unroll
        for (int reg = 0; reg < 4; ++reg) {
            const int t = t0 + wm + i * 16 + fq * 4 + reg;
            if (t < lim) {
                const int p = parent[t];
                const size_t xb = (size_t)t * FH + col;
                const float gi = acc[i][0][reg] + xproj[xb];
                const float go = acc[i][1][reg] + xproj[xb + HD];
                const float gf = acc[i][2][reg] + xproj[xb + 2 * HD];
                const float gu = acc[i][3][reg] + xproj[xb + 3 * HD];
                const float cp = c_buf[(size_t)(p + 1) * HD + col];
                const float c = fast_sig(gi) * fast_tanh(gu) + fast_sig(gf) * cp;
                const float h = fast_sig(go) * fast_tanh(c);
                c_buf[(size_t)(t + 1) * HD + col] = c;
                h_buf[(size_t)(t + 1) * HD + col] = f2bf(h);
                out[(size_t)t * HD + col] = h;
            }
        }
    }
}

// ---------------------------------------------------------------------------
// Large levels (count >= 1024): BK=32 m97 structure + XCD swizzle.
// Block: 128 nodes x 32 within-gate cols (=128 iofu rows: 4 gates x 32).
// ---------------------------------------------------------------------------
__global__ __launch_bounds__(256) void level_mfma(
    const float* __restrict__ xproj, const unsigned short* __restrict__ Whb,
    const int* __restrict__ parent, unsigned short* __restrict__ h_buf,
    float* __restrict__ c_buf, float* __restrict__ out,
    int start, int count)
{
    __shared__ unsigned short As[128 * 32];
    __shared__ unsigned short Bs[128 * 32];
    const int tid = threadIdx.x;
    const int wid = tid >> 6;
    const int lane = tid & 63;

    int id = blockIdx.y * gridDim.x + blockIdx.x;
    const int cpx = (gridDim.x * gridDim.y) >> 3;   // nwg %8==0 for count>=1024
    id = (id & 7) * cpx + (id >> 3);
    const int t0 = start + (id % gridDim.x) * 128;
    const int jg0 = (id / gridDim.x) * 32;

    const int lim = start + count;
    const int wm = (wid & 1) * 64;
    const int wn16 = (wid >> 1) * 16;

    const int srow = wid * 16 + (lane >> 2);
    const int sk = (lane & 3) * 8;
    const int tA0 = min(t0 + srow, lim - 1);
    const int tA1 = min(t0 + 64 + srow, lim - 1);
    const unsigned short* gA0 = h_buf + (size_t)(parent[tA0] + 1) * HD + sk;
    const unsigned short* gA1 = h_buf + (size_t)(parent[tA1] + 1) * HD + sk;
    const int r0 = srow, r1 = 64 + srow;
    const unsigned short* gB0 = Whb + (size_t)((r0 >> 5) * HD + jg0 + (r0 & 31)) * HD + sk;
    const unsigned short* gB1 = Whb + (size_t)((r1 >> 5) * HD + jg0 + (r1 & 31)) * HD + sk;
    unsigned short* lA0 = As + wid * 512;
    unsigned short* lA1 = As + 2048 + wid * 512;
    unsigned short* lB0 = Bs + wid * 512;
    unsigned short* lB1 = Bs + 2048 + wid * 512;

    f32x4 acc[4][4];
    #pragma unroll
    for (int i = 0; i < 4; ++i)
        #pragma unroll
        for (int g = 0; g < 4; ++g) { f32x4 z = {0.f, 0.f, 0.f, 0.f}; acc[i][g] = z; }

    const int fr = lane & 15;
    const int fk = (lane >> 4) * 8;

    for (int k0 = 0; k0 < HD; k0 += 32) {
        gload_lds16(gA0 + k0, lA0);
        gload_lds16(gA1 + k0, lA1);
        gload_lds16(gB0 + k0, lB0);
        gload_lds16(gB1 + k0, lB1);
        __syncthreads();

        s16x8 aF[4], bF[4];
        #pragma unroll
        for (int i = 0; i < 4; ++i)
            aF[i] = *(const s16x8*)&As[(wm + i * 16 + fr) * 32 + fk];
        #pragma unroll
        for (int g = 0; g < 4; ++g)
            bF[g] = *(const s16x8*)&Bs[(g * 32 + wn16 + fr) * 32 + fk];
        #pragma unroll
        for (int i = 0; i < 4; ++i)
            #pragma unroll
            for (int g = 0; g < 4; ++g)
                acc[i][g] = __builtin_amdgcn_mfma_f32_16x16x32_bf16(aF[i], bF[g], acc[i][g], 0, 0, 0);
        __syncthreads();
    }

    level_epilogue(acc, xproj, parent, h_buf, c_buf, out,
                   t0, lim, wm, jg0 + wn16 + fr, lane >> 4);
}

// ---------------------------------------------------------------------------
// Small/mid levels (count <= 512): BK=128 (8 K-iterations instead of 32) to
// cut the serial latency chain. 256B LDS rows -> XOR-swizzle (row&7)<<4 on
// BOTH the per-lane global source (linear LDS dest, rule #21) and ds_read.
// ---------------------------------------------------------------------------
__global__ __launch_bounds__(256) void level_mfma_bk128(
    const float* __restrict__ xproj, const unsigned short* __restrict__ Whb,
    const int* __restrict__ parent, unsigned short* __restrict__ h_buf,
    float* __restrict__ c_buf, float* __restrict__ out,
    int start, int count)
{
    __shared__ unsigned short As[128 * 128];   // 32 KB, [node][k], 256B rows
    __shared__ unsigned short Bs[128 * 128];   // 32 KB, [iofu-row][k]
    const int tid = threadIdx.x;
    const int wid = tid >> 6;
    const int lane = tid & 63;
    const int t0 = start + blockIdx.x * 128;
    const int jg0 = blockIdx.y * 32;
    const int lim = start + count;
    const int wm = (wid & 1) * 64;
    const int wn16 = (wid >> 1) * 16;

    // staging: 8 issues for A, 8 for B; issue q: linear byte p = q*4096 + tid*16
    // row = p>>8 = q*16 + tid/16 ; in-row byte = (tid&15)*16, XOR-swizzled source
    const int srow_b = tid >> 4;
    const int rowbyte = (tid & 15) * 16;
    const unsigned short* gA[8];
    const unsigned short* gB[8];
    #pragma unroll
    for (int q = 0; q < 8; ++q) {
        const int r = q * 16 + srow_b;
        const int sk = (rowbyte ^ ((r & 7) << 4)) >> 1;    // element offset in row
        const int tA = min(t0 + r, lim - 1);
        gA[q] = h_buf + (size_t)(parent[tA] + 1) * HD + sk;
        const int whrow = ((r >> 5) << 10) + jg0 + (r & 31);
        gB[q] = Whb + (size_t)whrow * HD + sk;
    }

    f32x4 acc[4][4];
    #pragma unroll
    for (int i = 0; i < 4; ++i)
        #pragma unroll
        for (int g = 0; g < 4; ++g) { f32x4 z = {0.f, 0.f, 0.f, 0.f}; acc[i][g] = z; }

    const int fr = lane & 15;
    const int fkb = (lane >> 4) * 16;   // byte offset of lane's 8-elem k-chunk

    for (int k0 = 0; k0 < HD; k0 += 128) {
        #pragma unroll
        for (int q = 0; q < 8; ++q) {
            gload_lds16(gA[q] + k0, (char*)As + q * 4096 + wid * 1024);
            gload_lds16(gB[q] + k0, (char*)Bs + q * 4096 + wid * 1024);
        }
        __syncthreads();

        #pragma unroll
        for (int kk = 0; kk < 4; ++kk) {
            s16x8 aF[4], bF[4];
            #pragma unroll
            for (int i = 0; i < 4; ++i) {
                const int r = wm + i * 16 + fr;
                const int byteIn = (kk * 64 + fkb) ^ ((r & 7) << 4);
                aF[i] = *(const s16x8*)((const char*)As + r * 256 + byteIn);
            }
            #pragma unroll
            for (int g = 0; g < 4; ++g) {
                const int r = g * 32 + wn16 + fr;
                const int byteIn = (kk * 64 + fkb) ^ ((r & 7) << 4);
                bF[g] = *(const s16x8*)((const char*)Bs + r * 256 + byteIn);
            }
            #pragma unroll
            for (int i = 0; i < 4; ++i)
                #pragma unroll
                for (int g = 0; g < 4; ++g)
                    acc[i][g] = __builtin_amdgcn_mfma_f32_16x16x32_bf16(aF[i], bF[g], acc[i][g], 0, 0, 0);
        }
        __syncthreads();
    }

    level_epilogue(acc, xproj, parent, h_buf, c_buf, out,
                   t0, lim, wm, jg0 + wn16 + fr, lane >> 4);
}

extern "C" void kernel_launch(void* const* d_in, const int* in_sizes, int n_in,
                              void* d_out, int out_size, void* d_ws, size_t ws_size,
                              hipStream_t stream) {
    const float* feat   = (const float*)d_in[0];
    const float* Wx     = (const float*)d_in[1];
    const float* bx     = (const float*)d_in[2];
    const float* Wh     = (const float*)d_in[3];
    const float* bh     = (const float*)d_in[4];
    const int*   parent = (const int*)d_in[5];
    const float* root_c = (const float*)d_in[6];
    const float* root_h = (const float*)d_in[7];
    float* out = (float*)d_out;

    char* ws = (char*)d_ws;
    float* xproj = (float*)ws;                          ws += (size_t)NN * FH * 4;
    float* c_buf = (float*)ws;                          ws += (size_t)(NN + 1) * HD * 4;
    unsigned short* feat_b = (unsigned short*)ws;       ws += (size_t)NN * FEAT * 2;
    unsigned short* Wx_b = (unsigned short*)ws;         ws += (size_t)FH * FEAT * 2;
    unsigned short* Wh_b = (unsigned short*)ws;         ws += (size_t)FH * HD * 2;
    unsigned short* h_buf = (unsigned short*)ws;        ws += (size_t)(NN + 1) * HD * 2;

    const size_t ntot = (size_t)NN * FEAT + (size_t)FH * FEAT + (size_t)FH * HD;
    convert_all_kernel<<<(unsigned)(ntot / 8 / 256), 256, 0, stream>>>(
        feat, Wx, Wh, feat_b, Wx_b, Wh_b);
    init_kernel<<<4, 256, 0, stream>>>(root_h, root_c, h_buf, c_buf);

    dim3 g1(NN / 128, FH / 128);
    xproj_mfma<<<g1, 256, 0, stream>>>(feat_b, Wx_b, bx, bh, xproj);

    for (int start = 0, sz = 1; start < NN; start += sz, sz *= 2) {
        const int count = (sz < NN - start) ? sz : (NN - start);
        dim3 g2((count + 127) / 128, HD / 32);
        if (count >= 1024)
            level_mfma<<<g2, 256, 0, stream>>>(xproj, Wh_b, parent, h_buf, c_buf,
                                               out, start, count);
        else
            level_mfma_bk128<<<g2, 256, 0, stream>>>(xproj, Wh_b, parent, h_buf,
                                                     c_buf, out, start, count);
    }
}